// Round 1
// 3745.538 us; speedup vs baseline: 1.5386x; 1.5386x over previous
//
#include <hip/hip_runtime.h>
#include <cmath>

#define DIM    256
#define LATENT 1024
#define BATCH  128
#define SEQT   512

typedef short  short8  __attribute__((ext_vector_type(8)));
typedef float  floatx4 __attribute__((ext_vector_type(4)));
typedef unsigned long long u64;

__device__ __forceinline__ short f2bf(float f) {
  union { float f; unsigned u; } v; v.f = f;
  unsigned u = v.u;
  unsigned r = (u + 0x7fffu + ((u >> 16) & 1u)) >> 16;   // RNE
  return (short)r;
}

// ---------------------------------------------------------------------------
// Kernel 1: xw[b,t,:] = x[b,t,:] @ Wx + b_in, stored to out[t][b][:] (fp32).
// (unchanged — correct, not the bottleneck)
// ---------------------------------------------------------------------------
__global__ __launch_bounds__(256) void xw_gemm(
    const float* __restrict__ x, const float* __restrict__ Win,
    const float* __restrict__ bin, float* __restrict__ out)
{
  __shared__ short lB[32 * 64 * 8];   // [(kt*4+q)=oct][c 0..63][j 0..7], 32 KB
  const int tid  = threadIdx.x;
  const int wave = tid >> 6;
  const int lane = tid & 63;
  const int q    = lane >> 4;
  const int ln   = lane & 15;
  const int m0   = blockIdx.x * 64;

  short8 afr[8];
  {
    const float* xrow = x + (size_t)(m0 + wave * 16 + ln) * DIM + q * 8;
    #pragma unroll
    for (int kt = 0; kt < 8; ++kt) {
      float4 v0 = *(const float4*)(xrow + kt * 32);
      float4 v1 = *(const float4*)(xrow + kt * 32 + 4);
      short8 a;
      a[0]=f2bf(v0.x); a[1]=f2bf(v0.y); a[2]=f2bf(v0.z); a[3]=f2bf(v0.w);
      a[4]=f2bf(v1.x); a[5]=f2bf(v1.y); a[6]=f2bf(v1.z); a[7]=f2bf(v1.w);
      afr[kt] = a;
    }
  }

  for (int s = 0; s < 16; ++s) {
    __syncthreads();
    {
      const int c  = tid & 63;
      const int o0 = tid >> 6;
      for (int oct = o0; oct < 32; oct += 4) {
        short8 w;
        #pragma unroll
        for (int j = 0; j < 8; ++j)
          w[j] = f2bf(Win[(size_t)(oct * 8 + j) * LATENT + s * 64 + c]);
        *(short8*)&lB[(oct * 64 + c) * 8] = w;
      }
    }
    __syncthreads();
    #pragma unroll
    for (int nt = 0; nt < 4; ++nt) {
      floatx4 acc0 = {0.f,0.f,0.f,0.f}, acc1 = {0.f,0.f,0.f,0.f};
      #pragma unroll
      for (int kt = 0; kt < 8; kt += 2) {
        short8 b0 = *(const short8*)&lB[(( kt   *4 + q) * 64 + nt*16 + ln) * 8];
        short8 b1 = *(const short8*)&lB[(((kt+1)*4 + q) * 64 + nt*16 + ln) * 8];
        acc0 = __builtin_amdgcn_mfma_f32_16x16x32_bf16(afr[kt],   b0, acc0, 0,0,0);
        acc1 = __builtin_amdgcn_mfma_f32_16x16x32_bf16(afr[kt+1], b1, acc1, 0,0,0);
      }
      floatx4 acc = acc0 + acc1;
      const int col = s*64 + nt*16 + ln;
      const float bv = bin[col];
      #pragma unroll
      for (int i = 0; i < 4; ++i) {
        int r = m0 + wave*16 + q*4 + i;       // flat row = b*SEQT + t
        int t = r & (SEQT - 1);
        int b = r >> 9;
        out[((size_t)t * BATCH + b) * LATENT + col] = acc[i] + bv;
      }
    }
  }
}

// ---------------------------------------------------------------------------
// Kernel 2: persistent recurrence, XCD-local sync.
// R2 change: the per-step flag wait was a 256-wave-per-XCD spin storm on a
// single 64B line (no backoff, all 4 waves of every wg polling with
// L1-bypassing loads). That saturated the flag line's cache bank, inflating
// poll RTs, delaying the arriving wgs' flag STORES behind the queue, and
// stealing issue slots from the co-resident computing wg (2 wg/CU).
// Now: ONLY WAVE 0 polls (waves 1-3 park on __syncthreads, zero traffic,
// zero issue pressure) with s_sleep(2) backoff between failed polls.
// ~10x lower poll request rate -> unloaded flag/ring latency.
// ---------------------------------------------------------------------------
__global__ __launch_bounds__(256) void rnn_persistent(
    float* __restrict__ out, const float* __restrict__ Win,
    unsigned short* __restrict__ ring, unsigned char* __restrict__ flags,
    int* __restrict__ wcnt)
{
  __shared__ short lW[128 * 16 * 8];   // [(kt*4+q)][n][j], 32 KB
  __shared__ float red[4][16][16];     // 4 KB
  __shared__ int s_g, s_wid, s_bad;

  const int tid  = threadIdx.x;
  const int wave = tid >> 6;
  const int lane = tid & 63;
  const int q    = lane >> 4;
  const int ln   = lane & 15;

  if (tid == 0) {
    unsigned xcc;
    asm volatile("s_getreg_b32 %0, hwreg(HW_REG_XCC_ID)" : "=s"(xcc));
    xcc &= 7u;
    s_g   = (int)xcc;
    s_wid = atomicAdd(&wcnt[xcc], 1) & 63;   // within-XCD slot 0..63
    s_bad = 0;
  }
  __syncthreads();
  const int g    = s_g;
  const int wid  = s_wid;
  const int col0 = wid * 16;
  const int row0 = g * 16;
  unsigned char* fl = flags + (size_t)g * (SEQT * 64);

  // Stage Wh[:, col0..col0+16) (rows DIM.. of W_in) swizzled to bf16.
  for (int i = tid; i < 128 * 16; i += 256) {   // i = oct*16 + n ; k = oct*8+j
    const int oct = i >> 4, n = i & 15;
    short8 w;
    #pragma unroll
    for (int j = 0; j < 8; ++j)
      w[j] = f2bf(Win[(size_t)(DIM + oct*8 + j) * LATENT + col0 + n]);
    *(short8*)&lW[i * 8] = w;
  }

  const int erow = tid >> 4, ecol = tid & 15;
  float* outp = out + (size_t)(row0 + erow) * LATENT + col0 + ecol;
  unsigned short* ringp = ring + (size_t)(row0 + erow) * LATENT + col0 + ecol;
  __syncthreads();

  for (int t = 0; t < SEQT; ++t) {
    // xw prefetch (owner-exclusive location, plain load) — overlaps the wait
    float xw = outp[(size_t)t * (BATCH * LATENT)];
    float hsum = 0.f;
    if (t > 0) {
      // ---- wait for all 64 peer flags of step t-1 (one 64B line) ----
      // Wave 0 is the sole poller; s_sleep backoff keeps the flag line's
      // bank unloaded and yields issue slots to the co-resident wg.
      const unsigned char* fbase = fl + (size_t)(t - 1) * 64;
      if (wave == 0) {
        int guard = s_bad ? 1 : 4000000;
        for (;;) {
          unsigned v = __hip_atomic_load((const unsigned char*)(fbase + lane),
                                         __ATOMIC_RELAXED,
                                         __HIP_MEMORY_SCOPE_AGENT);
          if (__all(v != 0)) break;
          if (--guard <= 0) { s_bad = 1; break; }   // terminate, don't hang
          __builtin_amdgcn_s_sleep(2);
        }
      }
      __syncthreads();   // release waves 1-3; also orders ring reads after poll

      // ---- ring read: rows row0+ln, this wave's K range, L1-bypassing ----
      const unsigned short* rbase =
          ring + ((size_t)((t - 1) & 3) * BATCH + row0 + ln) * LATENT
               + wave * 256 + q * 8;
      short8 a[8];
      #pragma unroll
      for (int kk = 0; kk < 8; ++kk) {
        union { u64 w[2]; short8 s; } u;
        u.w[0] = __hip_atomic_load((const u64*)(rbase + kk * 32),
                                   __ATOMIC_RELAXED, __HIP_MEMORY_SCOPE_AGENT);
        u.w[1] = __hip_atomic_load((const u64*)(rbase + kk * 32 + 4),
                                   __ATOMIC_RELAXED, __HIP_MEMORY_SCOPE_AGENT);
        a[kk] = u.s;
      }

      floatx4 acc0 = {0.f,0.f,0.f,0.f}, acc1 = {0.f,0.f,0.f,0.f};
      #pragma unroll
      for (int kk = 0; kk < 4; ++kk) {
        const int kt  = wave * 8 + kk;
        const int kt2 = wave * 8 + 4 + kk;
        short8 b  = *(const short8*)&lW[((kt  * 4 + q) * 16 + ln) * 8];
        short8 b2 = *(const short8*)&lW[((kt2 * 4 + q) * 16 + ln) * 8];
        acc0 = __builtin_amdgcn_mfma_f32_16x16x32_bf16(a[kk],     b,  acc0, 0,0,0);
        acc1 = __builtin_amdgcn_mfma_f32_16x16x32_bf16(a[4 + kk], b2, acc1, 0,0,0);
      }
      floatx4 acc = acc0 + acc1;
      #pragma unroll
      for (int i = 0; i < 4; ++i) red[wave][q*4 + i][ln] = acc[i];
      __syncthreads();
      hsum = red[0][erow][ecol] + red[1][erow][ecol]
           + red[2][erow][ecol] + red[3][erow][ecol];
    }

    const float h = tanhf(xw + hsum);
    outp [(size_t)t      * (BATCH * LATENT)] = h;                        // fp32 output
    ringp[(size_t)(t & 3) * (BATCH * LATENT)] = (unsigned short)f2bf(h); // bf16 ring (write-through -> L2)
    __syncthreads();   // drains all waves' stores (vmcnt(0) before s_barrier)
    if (tid == 0)
      *(volatile unsigned char*)(fl + (size_t)t * 64 + wid) = (unsigned char)1;
  }
}

// ---------------------------------------------------------------------------
extern "C" void kernel_launch(void* const* d_in, const int* in_sizes, int n_in,
                              void* d_out, int out_size, void* d_ws, size_t ws_size,
                              hipStream_t stream) {
  (void)in_sizes; (void)n_in; (void)out_size; (void)ws_size;
  const float* x   = (const float*)d_in[0];
  const float* Win = (const float*)d_in[1];
  const float* bin = (const float*)d_in[2];
  float* out = (float*)d_out;

  // ws layout: [0,32) per-XCD slot counters | [4096, +256K) flags | ring 1MB
  int*            wcnt  = (int*)d_ws;
  unsigned char*  flags = (unsigned char*)d_ws + 4096;
  unsigned short* ring  = (unsigned short*)((char*)d_ws + 4096 + 8 * SEQT * 64);

  hipMemsetAsync(d_ws, 0, 4096 + 8 * SEQT * 64, stream);
  xw_gemm<<<dim3(65536 / 64), dim3(256), 0, stream>>>(x, Win, bin, out);

  void* args[] = { &out, &Win, &ring, &flags, &wcnt };
  hipLaunchCooperativeKernel((void*)rnn_persistent, dim3(512), dim3(256),
                             args, 0, stream);
}